// Round 3
// baseline (358.357 us; speedup 1.0000x reference)
//
#include <hip/hip_runtime.h>
#include <math.h>

#define N 8192
#define H 128
#define NEV 64
#define SS 20
#define MAXD 512
#define MAXDIRTY 128
#define RPB 32

// ---------------------------------------------------------------------------
// k_init: fu[n] = first updater-slot id (e*2+r; r=0 -> row v[e], r=1 -> row u[e]),
// zsrc[i] = canonical slot if node updated before event e else -1,
// wslot[i] = canonical slot for this update, dtv[i] = precomputed dt,
// deg/dcnt zeroed. Single block; fu built in LDS (coherent via barriers).
// ---------------------------------------------------------------------------
__global__ __launch_bounds__(256) void k_init(
    const int* __restrict__ u, const int* __restrict__ v,
    const float* __restrict__ t, const float* __restrict__ lastt,
    int* __restrict__ fu, int* __restrict__ zsrc, int* __restrict__ wslot,
    float* __restrict__ dtv, int* __restrict__ deg, int* __restrict__ dcnt)
{
    __shared__ int fuL[N];   // 32 KB
    const int tid = threadIdx.x;
    for (int i = tid; i < N; i += 256) fuL[i] = 0x7FFFFFFF;
    if (tid < 128) { deg[tid] = 0; dcnt[tid] = 0; }
    __syncthreads();
    if (tid < 2 * NEV) {
        const int e = tid >> 1, i = tid & 1;
        const int node = i ? u[e] : v[e];       // idx0 -> row v, idx1 -> row u
        atomicMin(&fuL[node], tid);
    }
    __syncthreads();
    for (int i = tid; i < N; i += 256) fu[i] = fuL[i];
    if (tid < 2 * NEV) {
        const int e = tid >> 1, i = tid & 1;
        const int node = i ? u[e] : v[e];
        const int f = fuL[node];
        wslot[tid] = f;
        zsrc[tid] = (f < 2 * e) ? f : -1;       // updated strictly before event e?
        const int dtn = i ? v[e] : u[e];        // crossed: row v uses let[u], row u let[v]
        int pt = -1;
        for (int e2 = e - 1; e2 >= 0; --e2)
            if (u[e2] == dtn || v[e2] == dtn) { pt = e2; break; }
        const float lv = (pt >= 0) ? t[pt] : lastt[dtn];
        dtv[tid] = t[e] - lv;
    }
}

// ---------------------------------------------------------------------------
// k_emb: h_tab = emb @ W_h.T + b_h ; z_out = emb copy ; d0/d1 rate dots.
// ---------------------------------------------------------------------------
__global__ __launch_bounds__(512) void k_emb(
    const float* __restrict__ emb, const float* __restrict__ W_h,
    const float* __restrict__ b_h, const float* __restrict__ W_om,
    float* __restrict__ h_tab, float* __restrict__ z_out,
    float* __restrict__ d0, float* __restrict__ d1)
{
    const int tid = threadIdx.x;
    const int c = tid & 127;
    const int s = tid >> 7;             // 0..3
    const int r0 = blockIdx.x * RPB;

    __shared__ __align__(16) float z4[4 * 128];
    __shared__ float pr[8 * 128];

    float whr[32];
#pragma unroll
    for (int i = 0; i < 32; ++i) whr[i] = W_h[c * H + s * 32 + i];
    const float bh_c = b_h[c];

    const int lane = tid & 63;
    const int wid = tid >> 6;
    const int kof = (wid >= 4) ? 256 : 0;
    const float wk_l = W_om[kof + lane]      + W_om[kof + 128 + lane];
    const float wk_h = W_om[kof + 64 + lane] + W_om[kof + 192 + lane];

    for (int b = 0; b < RPB / 4; ++b) {
        const int rbase = r0 + b * 4;
        __syncthreads();
        const float zv = emb[(size_t)rbase * H + tid];
        z4[tid] = zv;
        z_out[(size_t)rbase * H + tid] = zv;
        __syncthreads();

#pragma unroll
        for (int rr = 0; rr < 4; ++rr) {
            float a = 0.f;
#pragma unroll
            for (int i4 = 0; i4 < 8; ++i4) {
                const float4 zz = *(const float4*)&z4[rr * 128 + s * 32 + i4 * 4];
                a += zz.x * whr[i4 * 4] + zz.y * whr[i4 * 4 + 1] +
                     zz.z * whr[i4 * 4 + 2] + zz.w * whr[i4 * 4 + 3];
            }
            pr[(s * 4 + rr) * 128 + c] = a;
        }
        {
            const int rr = wid & 3;
            float val = z4[rr * 128 + lane] * wk_l + z4[rr * 128 + 64 + lane] * wk_h;
#pragma unroll
            for (int off = 32; off > 0; off >>= 1) val += __shfl_xor(val, off);
            if (lane == 0) {
                if (wid < 4) d0[rbase + rr] = val;
                else         d1[rbase + rr] = val;
            }
        }
        __syncthreads();
        {
            const int rr = s;
            const float h = pr[(0 * 4 + rr) * 128 + c] + pr[(1 * 4 + rr) * 128 + c] +
                            pr[(2 * 4 + rr) * 128 + c] + pr[(3 * 4 + rr) * 128 + c] + bh_c;
            h_tab[(size_t)(rbase + rr) * H + c] = h;
        }
    }
}

// ---------------------------------------------------------------------------
// k_nbr: compact neighbor lists for the 128 (event,side) rows.
// ---------------------------------------------------------------------------
__global__ __launch_bounds__(256) void k_nbr(
    const int* __restrict__ u, const int* __restrict__ v,
    const float* __restrict__ A, const float* __restrict__ S,
    int* __restrict__ deg, float* __restrict__ sumv,
    int* __restrict__ nbr_i, float* __restrict__ nbr_e)
{
    const int slot = blockIdx.x;
    const int e = slot >> 1, side = slot & 1;
    const int row = (side == 0) ? v[e] : u[e];
    const size_t base = (size_t)row * N;
    const int tid = threadIdx.x;
    float lsum = 0.f;
    for (int j = tid; j < N; j += 256) {
        if (A[base + j] > 0.f) {
            const float ev = expf(S[base + j]);
            lsum += ev;
            const int p = atomicAdd(&deg[slot], 1);
            if (p < MAXD) {
                nbr_i[slot * MAXD + p] = j;
                nbr_e[slot * MAXD + p] = ev;
            }
        }
    }
    __shared__ float rs[256];
    rs[tid] = lsum;
    __syncthreads();
    for (int off = 128; off > 0; off >>= 1) {
        if (tid < off) rs[tid] += rs[tid + off];
        __syncthreads();
    }
    if (tid == 0) sumv[slot] = rs[0];
}

// ---------------------------------------------------------------------------
// k_dm: Mstat over static (not-yet-updated) neighbors + dirty list with slots.
// ---------------------------------------------------------------------------
__global__ __launch_bounds__(128) void k_dm(
    const int* __restrict__ deg, const float* __restrict__ sumv,
    const int* __restrict__ nbr_i, const float* __restrict__ nbr_e,
    const int* __restrict__ fu, const float* __restrict__ h_tab,
    float* __restrict__ Mstat, int* __restrict__ dcnt,
    int* __restrict__ dl_s, float* __restrict__ dl_q)
{
    const int slot = blockIdx.x;
    const int e = slot >> 1;
    const int c = threadIdx.x;
    const int d = min(deg[slot], MAXD);
    const float rinv = 1.f / (sumv[slot] + 1e-7f);
    float m = -INFINITY;
    for (int j0 = 0; j0 < d; ++j0) {
        const int j = nbr_i[slot * MAXD + j0];
        if (fu[j] >= 2 * e)
            m = fmaxf(m, nbr_e[slot * MAXD + j0] * rinv * h_tab[(size_t)j * H + c]);
    }
    Mstat[slot * H + c] = m;
    for (int j0 = c; j0 < d; j0 += 128) {
        const int j = nbr_i[slot * MAXD + j0];
        const int f = fu[j];
        if (f < 2 * e) {
            const int p = atomicAdd(&dcnt[slot], 1);
            if (p < MAXDIRTY) {
                dl_s[slot * MAXDIRTY + p] = f;
                dl_q[slot * MAXDIRTY + p] = nbr_e[slot * MAXD + j0] * rinv;
            }
        }
    }
}

// ---------------------------------------------------------------------------
// k_ls: lam (block 0) + survival (blocks 1..SS).
// ---------------------------------------------------------------------------
__global__ __launch_bounds__(64) void k_ls(
    const int* __restrict__ u, const int* __restrict__ v, const int* __restrict__ kk,
    const int* __restrict__ u_o, const int* __restrict__ v_o,
    const float* __restrict__ d0, const float* __restrict__ d1,
    const float* __restrict__ psi, const float* __restrict__ b_om,
    float* __restrict__ lamout, float* __restrict__ svout)
{
    const int b = threadIdx.x;
    if (blockIdx.x == 0) {
        if (b < NEV) {
            const int kv = kk[b];
            const float* dk = kv ? d1 : d0;
            const float g = 0.5f * (dk[u[b]] + dk[v[b]]) + b_om[kv];
            const float ps = psi[kv];
            const float x = fminf(75.f, fmaxf(-75.f, g / ps));
            lamout[b] = ps * log1pf(expf(x));
        }
    } else {
        const int s = blockIdx.x - 1;
        const float p0 = psi[0], p1 = psi[1], bo0 = b_om[0], bo1 = b_om[1];
        const int vo = v_o[b * SS + s], uo = u_o[b * SS + s];
        float g, x;
        g = 0.5f * (d0[u[b]] + d0[vo]) + bo0; x = fminf(75.f, fmaxf(-75.f, g / p0));
        const float ru0 = p0 * log1pf(expf(x));
        g = 0.5f * (d1[u[b]] + d1[vo]) + bo1; x = fminf(75.f, fmaxf(-75.f, g / p1));
        const float ru1 = p1 * log1pf(expf(x));
        g = 0.5f * (d1[v[b]] + d1[uo]) + bo1; x = fminf(75.f, fmaxf(-75.f, g / p1));
        const float rv1 = p1 * log1pf(expf(x));
        float val = 2.f * (ru0 + ru1) + rv1;
#pragma unroll
        for (int off = 32; off > 0; off >>= 1) val += __shfl_xor(val, off);
        if (b == 0) svout[s] = val / (float)SS;
    }
}

// ---------------------------------------------------------------------------
// k_seq: 64-event scan, 1 block x 512, 3 barriers/event, all state in LDS.
// tid = c*4+s : column c (0..127), K-chunk s (0..3). shfl_xor(1),(2) reduces
// the 4 chunks inside each wave. s=0/1 also own {hs_v,hs_u} and row r=s;
// s=2/3 own the z-row reads.
// ---------------------------------------------------------------------------
constexpr int KSEQ_LDS_BYTES = (128 * 128 * 2 + 128 * 4 + 128 * 2 + 128 + /*ints*/ 64 * 2 + 128 * 4) * 4;

__global__ __launch_bounds__(512, 1) void k_seq(
    const int* __restrict__ u, const int* __restrict__ v,
    const float* __restrict__ W_S, const float* __restrict__ W_R,
    const float* __restrict__ W_t, const float* __restrict__ W_h,
    const float* __restrict__ b_h,
    const int* __restrict__ deg, const int* __restrict__ dcnt,
    const int* __restrict__ dl_s, const float* __restrict__ dl_q,
    const float* __restrict__ Mstat,
    const int* __restrict__ zsrc, const int* __restrict__ wslot,
    const float* __restrict__ dtv,
    float* __restrict__ z_out)
{
    extern __shared__ float lds[];
    float* z_upd = lds;                 // [128][128] latest z per canonical slot
    float* h_upd = z_upd + 128 * 128;   // [128][128] latest h per canonical slot
    float* hz    = h_upd + 128 * 128;   // [c'][4] = {hs_v, hs_u, z_v, z_u}
    float* znw   = hz + 128 * 4;        // [c'][2] = {znew_v, znew_u}
    float* dtv_l = znw + 128 * 2;       // [128]
    int*   ib    = (int*)(dtv_l + 128);
    int* ev_u_l  = ib;                  // 64
    int* ev_v_l  = ib + 64;             // 64
    int* zsrc_l  = ib + 128;            // 128
    int* wslot_l = ib + 256;            // 128
    int* deg_l   = ib + 384;            // 128
    int* dcnt_l  = ib + 512;            // 128

    const int tid = threadIdx.x;
    const int c = tid >> 2;             // 0..127
    const int s = tid & 3;              // 0..3

    float wsr[32], wrr[32], whr[32];
#pragma unroll
    for (int i = 0; i < 32; ++i) {
        wsr[i] = W_S[c * H + s * 32 + i];
        wrr[i] = W_R[c * H + s * 32 + i];
        whr[i] = W_h[c * H + s * 32 + i];
    }
    const float wt_c = W_t[c];
    const float bh_c = b_h[c];

    if (tid < NEV) { ev_u_l[tid] = u[tid]; ev_v_l[tid] = v[tid]; }
    if (tid >= 64 && tid < 192)  { const int i = tid - 64;  zsrc_l[i] = zsrc[i]; wslot_l[i] = wslot[i]; }
    if (tid >= 192 && tid < 320) { const int i = tid - 192; deg_l[i] = deg[i]; dcnt_l[i] = dcnt[i]; }
    if (tid >= 320 && tid < 448) { const int i = tid - 320; dtv_l[i] = dtv[i]; }
    __syncthreads();

    // prefetch for event 0
    float mpf = 0.f, dlq0 = 0.f, zpf = 0.f;
    int dls0 = 0;
    if (s < 2) {
        mpf  = Mstat[s * H + c];
        dls0 = dl_s[s * MAXDIRTY];
        dlq0 = dl_q[s * MAXDIRTY];
    } else {
        const int sl = zsrc_l[s - 2];
        if (sl < 0) {
            const int node = (s == 3) ? ev_u_l[0] : ev_v_l[0];
            zpf = z_out[(size_t)node * H + c];
        }
    }

    for (int e = 0; e < NEV; ++e) {
        const int uu = ev_u_l[e], vv = ev_v_l[e];
        const bool dup = (uu == vv);
        float dtv_r = 0.f; int wsl_r = 0;
        if (s < 2) { dtv_r = dtv_l[e * 2 + s]; wsl_r = wslot_l[e * 2 + s]; }

#pragma unroll
        for (int i = 0; i < 32; ++i)
            asm volatile("" : "+v"(wsr[i]), "+v"(wrr[i]), "+v"(whr[i]));

        // ---- Phase A: hz = {hs_v, hs_u, z_v, z_u} ----
        if (s < 2) {
            const int slot = e * 2 + s;
            float m = mpf;
            const int nd = min(dcnt_l[slot], MAXDIRTY);
            if (nd > 0) {
                m = fmaxf(m, dlq0 * h_upd[dls0 * 128 + c]);
                for (int p = 1; p < nd; ++p) {
                    const int f2 = dl_s[slot * MAXDIRTY + p];
                    const float q2 = dl_q[slot * MAXDIRTY + p];
                    m = fmaxf(m, q2 * h_upd[f2 * 128 + c]);
                }
            }
            hz[c * 4 + s] = (deg_l[slot] > 0) ? 1.f / (1.f + __expf(-m)) : 0.f;
        } else {
            const int sl = zsrc_l[e * 2 + (s - 2)];
            hz[c * 4 + s] = (sl >= 0) ? z_upd[sl * 128 + c] : zpf;
        }
        __syncthreads();               // B1: hz ready

        // prefetch for e+1 (issued here so the vmcnt drain lands at B2,
        // hidden under the phase-B matvec)
        if (e + 1 < NEV) {
            if (s < 2) {
                mpf  = Mstat[((e + 1) * 2 + s) * H + c];
                dls0 = dl_s[((e + 1) * 2 + s) * MAXDIRTY];
                dlq0 = dl_q[((e + 1) * 2 + s) * MAXDIRTY];
            } else {
                const int nsl = zsrc_l[(e + 1) * 2 + (s - 2)];
                if (nsl < 0) {
                    const int node = (s == 3) ? ev_u_l[e + 1] : ev_v_l[e + 1];
                    zpf = z_out[(size_t)node * H + c];
                }
            }
        }

        // ---- Phase B: g[r][c] = hs_r.W_S[c] + z_r.W_R[c] + dt_r*W_t[c] ----
        float a0 = 0.f, a1 = 0.f;
#pragma unroll
        for (int i = 0; i < 32; ++i) {
            const float4 vz = *(const float4*)&hz[(s * 32 + i) * 4];
            a0 += vz.x * wsr[i] + vz.z * wrr[i];
            a1 += vz.y * wsr[i] + vz.w * wrr[i];
        }
        a0 += __shfl_xor(a0, 1); a0 += __shfl_xor(a0, 2);
        a1 += __shfl_xor(a1, 1); a1 += __shfl_xor(a1, 2);
        if (s < 2) {
            const float g = ((s == 0) ? a0 : a1) + dtv_r * wt_c;
            const float zv = 1.f / (1.f + __expf(-g));
            znw[c * 2 + s] = zv;
            if (!(dup && s == 0)) z_upd[wsl_r * 128 + c] = zv;   // u-row wins on dup
        }
        __syncthreads();               // B2: znw / z_upd ready

        // ---- Phase C: h_new[r][c] = W_h[c] . znew_r + b_h[c] ----
        float b0 = 0.f, b1 = 0.f;
#pragma unroll
        for (int i = 0; i < 32; ++i) {
            const float2 zz = *(const float2*)&znw[(s * 32 + i) * 2];
            b0 += zz.x * whr[i];
            b1 += zz.y * whr[i];
        }
        b0 += __shfl_xor(b0, 1); b0 += __shfl_xor(b0, 2);
        b1 += __shfl_xor(b1, 1); b1 += __shfl_xor(b1, 2);
        if (s < 2 && !(dup && s == 0))
            h_upd[wsl_r * 128 + c] = ((s == 0) ? b0 : b1) + bh_c;
        __syncthreads();               // B3: h_upd/z_upd visible for next A
    }

    // ---- flush updated z rows (canonical slots only) ----
    const int sl = tid >> 2, q = tid & 3;
    if (wslot_l[sl] == sl) {
        const int node = (sl & 1) ? ev_u_l[sl >> 1] : ev_v_l[sl >> 1];
        float4* dst = (float4*)&z_out[(size_t)node * H + q * 32];
        const float4* src = (const float4*)&z_upd[sl * 128 + q * 32];
#pragma unroll
        for (int i = 0; i < 8; ++i) dst[i] = src[i];
    }
}

// ---------------------------------------------------------------------------
extern "C" void kernel_launch(void* const* d_in, const int* in_sizes, int n_in,
                              void* d_out, int out_size, void* d_ws, size_t ws_size,
                              hipStream_t stream)
{
    const int*   u        = (const int*)d_in[0];
    const int*   v        = (const int*)d_in[1];
    const float* t        = (const float*)d_in[2];
    const int*   k        = (const int*)d_in[3];
    const int*   u_others = (const int*)d_in[4];
    const int*   v_others = (const int*)d_in[5];
    const float* A        = (const float*)d_in[6];
    const float* S        = (const float*)d_in[7];
    const float* emb      = (const float*)d_in[8];
    const float* lastt    = (const float*)d_in[9];
    const float* W_S      = (const float*)d_in[10];
    const float* W_R      = (const float*)d_in[11];
    const float* W_t      = (const float*)d_in[12];
    const float* W_h      = (const float*)d_in[13];
    const float* b_h      = (const float*)d_in[14];
    const float* psi      = (const float*)d_in[15];
    const float* W_om     = (const float*)d_in[16];
    const float* b_om     = (const float*)d_in[17];
    (void)in_sizes; (void)n_in; (void)out_size; (void)ws_size;

    float* wsf   = (float*)d_ws;
    float* h_tab = wsf;                           // N*H
    float* d0    = h_tab + (size_t)N * H;         // N
    float* d1    = d0 + N;                        // N
    float* sumv  = d1 + N;                        // 128
    float* nbre  = sumv + 128;                    // 128*MAXD
    float* Mstat = nbre + 128 * MAXD;             // 128*H
    float* dl_q  = Mstat + 128 * H;               // 128*MAXDIRTY
    float* dtv   = dl_q + 128 * MAXDIRTY;         // 128
    int*   deg   = (int*)(dtv + 128);             // 128
    int*   dcnt  = deg + 128;                     // 128
    int*   nbri  = dcnt + 128;                    // 128*MAXD
    int*   dl_s  = nbri + 128 * MAXD;             // 128*MAXDIRTY
    int*   fu    = dl_s + 128 * MAXDIRTY;         // N
    int*   zsrc  = fu + N;                        // 128
    int*   wslot = zsrc + 128;                    // 128

    float* out    = (float*)d_out;
    float* lamout = out;            // [64]
    float* svout  = out + NEV;      // [20]
    float* z_out  = out + NEV + SS; // [N*H]

    hipFuncSetAttribute((const void*)k_seq,
                        hipFuncAttributeMaxDynamicSharedMemorySize,
                        KSEQ_LDS_BYTES);

    k_init<<<1, 256, 0, stream>>>(u, v, t, lastt, fu, zsrc, wslot, dtv, deg, dcnt);
    k_emb<<<N / RPB, 512, 0, stream>>>(emb, W_h, b_h, W_om, h_tab, z_out, d0, d1);
    k_nbr<<<128, 256, 0, stream>>>(u, v, A, S, deg, sumv, nbri, nbre);
    k_dm<<<128, 128, 0, stream>>>(deg, sumv, nbri, nbre, fu, h_tab, Mstat, dcnt, dl_s, dl_q);
    k_ls<<<SS + 1, 64, 0, stream>>>(u, v, k, u_others, v_others, d0, d1, psi, b_om, lamout, svout);
    k_seq<<<1, 512, KSEQ_LDS_BYTES, stream>>>(u, v, W_S, W_R, W_t, W_h, b_h,
                                              deg, dcnt, dl_s, dl_q, Mstat,
                                              zsrc, wslot, dtv, z_out);
}

// Round 4
// 179.078 us; speedup vs baseline: 2.0011x; 2.0011x over previous
//
#include <hip/hip_runtime.h>
#include <math.h>

#define N 8192
#define H 128
#define NEV 64
#define SS 20
#define MAXD 512
#define MAXDIRTY 128
#define RPB 32

// ---------------------------------------------------------------------------
// k_init: fu[n] = first updater-slot id (slot = e*2+i; i=0 -> row v[e],
// i=1 -> row u[e]); zsrc[slot] = canonical slot if node updated before event e
// else -1; wslot[slot] = canonical slot; dtv[slot] = precomputed dt.
// Zeroes deg/dcnt/needh.
// ---------------------------------------------------------------------------
__global__ __launch_bounds__(256) void k_init(
    const int* __restrict__ u, const int* __restrict__ v,
    const float* __restrict__ t, const float* __restrict__ lastt,
    int* __restrict__ fu, int* __restrict__ zsrc, int* __restrict__ wslot,
    float* __restrict__ dtv, int* __restrict__ deg, int* __restrict__ dcnt,
    int* __restrict__ needh)
{
    __shared__ int fuL[N];   // 32 KB
    const int tid = threadIdx.x;
    for (int i = tid; i < N; i += 256) fuL[i] = 0x7FFFFFFF;
    if (tid < 128) { deg[tid] = 0; dcnt[tid] = 0; }
    if (tid < NEV) needh[tid] = 0;
    __syncthreads();
    if (tid < 2 * NEV) {
        const int e = tid >> 1, i = tid & 1;
        const int node = i ? u[e] : v[e];       // i=0 -> row v, i=1 -> row u
        atomicMin(&fuL[node], tid);
    }
    __syncthreads();
    for (int i = tid; i < N; i += 256) fu[i] = fuL[i];
    if (tid < 2 * NEV) {
        const int e = tid >> 1, i = tid & 1;
        const int node = i ? u[e] : v[e];
        const int f = fuL[node];
        wslot[tid] = f;
        zsrc[tid] = (f < 2 * e) ? f : -1;       // updated strictly before event e?
        const int dtn = i ? v[e] : u[e];        // crossed: row v uses let[u], row u let[v]
        int pt = -1;
        for (int e2 = e - 1; e2 >= 0; --e2)
            if (u[e2] == dtn || v[e2] == dtn) { pt = e2; break; }
        const float lv = (pt >= 0) ? t[pt] : lastt[dtn];
        dtv[tid] = t[e] - lv;
    }
}

// ---------------------------------------------------------------------------
// k_emb: h_tab = emb @ W_h.T + b_h ; z_out = emb copy ; d0/d1 rate dots.
// ---------------------------------------------------------------------------
__global__ __launch_bounds__(512) void k_emb(
    const float* __restrict__ emb, const float* __restrict__ W_h,
    const float* __restrict__ b_h, const float* __restrict__ W_om,
    float* __restrict__ h_tab, float* __restrict__ z_out,
    float* __restrict__ d0, float* __restrict__ d1)
{
    const int tid = threadIdx.x;
    const int c = tid & 127;
    const int s = tid >> 7;             // 0..3
    const int r0 = blockIdx.x * RPB;

    __shared__ __align__(16) float z4[4 * 128];
    __shared__ float pr[8 * 128];

    float whr[32];
#pragma unroll
    for (int i = 0; i < 32; ++i) whr[i] = W_h[c * H + s * 32 + i];
    const float bh_c = b_h[c];

    const int lane = tid & 63;
    const int wid = tid >> 6;
    const int kof = (wid >= 4) ? 256 : 0;
    const float wk_l = W_om[kof + lane]      + W_om[kof + 128 + lane];
    const float wk_h = W_om[kof + 64 + lane] + W_om[kof + 192 + lane];

    for (int b = 0; b < RPB / 4; ++b) {
        const int rbase = r0 + b * 4;
        __syncthreads();
        const float zv = emb[(size_t)rbase * H + tid];
        z4[tid] = zv;
        z_out[(size_t)rbase * H + tid] = zv;
        __syncthreads();

#pragma unroll
        for (int rr = 0; rr < 4; ++rr) {
            float a = 0.f;
#pragma unroll
            for (int i4 = 0; i4 < 8; ++i4) {
                const float4 zz = *(const float4*)&z4[rr * 128 + s * 32 + i4 * 4];
                a += zz.x * whr[i4 * 4] + zz.y * whr[i4 * 4 + 1] +
                     zz.z * whr[i4 * 4 + 2] + zz.w * whr[i4 * 4 + 3];
            }
            pr[(s * 4 + rr) * 128 + c] = a;
        }
        {
            const int rr = wid & 3;
            float val = z4[rr * 128 + lane] * wk_l + z4[rr * 128 + 64 + lane] * wk_h;
#pragma unroll
            for (int off = 32; off > 0; off >>= 1) val += __shfl_xor(val, off);
            if (lane == 0) {
                if (wid < 4) d0[rbase + rr] = val;
                else         d1[rbase + rr] = val;
            }
        }
        __syncthreads();
        {
            const int rr = s;
            const float h = pr[(0 * 4 + rr) * 128 + c] + pr[(1 * 4 + rr) * 128 + c] +
                            pr[(2 * 4 + rr) * 128 + c] + pr[(3 * 4 + rr) * 128 + c] + bh_c;
            h_tab[(size_t)(rbase + rr) * H + c] = h;
        }
    }
}

// ---------------------------------------------------------------------------
// k_nbr: compact neighbor lists for the 128 (event,side) rows.
// ---------------------------------------------------------------------------
__global__ __launch_bounds__(256) void k_nbr(
    const int* __restrict__ u, const int* __restrict__ v,
    const float* __restrict__ A, const float* __restrict__ S,
    int* __restrict__ deg, float* __restrict__ sumv,
    int* __restrict__ nbr_i, float* __restrict__ nbr_e)
{
    const int slot = blockIdx.x;
    const int e = slot >> 1, side = slot & 1;
    const int row = (side == 0) ? v[e] : u[e];
    const size_t base = (size_t)row * N;
    const int tid = threadIdx.x;
    float lsum = 0.f;
    for (int j = tid; j < N; j += 256) {
        if (A[base + j] > 0.f) {
            const float ev = expf(S[base + j]);
            lsum += ev;
            const int p = atomicAdd(&deg[slot], 1);
            if (p < MAXD) {
                nbr_i[slot * MAXD + p] = j;
                nbr_e[slot * MAXD + p] = ev;
            }
        }
    }
    __shared__ float rs[256];
    rs[tid] = lsum;
    __syncthreads();
    for (int off = 128; off > 0; off >>= 1) {
        if (tid < off) rs[tid] += rs[tid + off];
        __syncthreads();
    }
    if (tid == 0) sumv[slot] = rs[0];
}

// ---------------------------------------------------------------------------
// k_dm: Mstat over static neighbors + dirty list (with canonical slots) +
// needh[e'] flag for events whose h rows are later consumed.
// ---------------------------------------------------------------------------
__global__ __launch_bounds__(128) void k_dm(
    const int* __restrict__ deg, const float* __restrict__ sumv,
    const int* __restrict__ nbr_i, const float* __restrict__ nbr_e,
    const int* __restrict__ fu, const float* __restrict__ h_tab,
    float* __restrict__ Mstat, int* __restrict__ dcnt,
    int* __restrict__ dl_s, float* __restrict__ dl_q,
    int* __restrict__ needh)
{
    const int slot = blockIdx.x;
    const int e = slot >> 1;
    const int c = threadIdx.x;
    const int d = min(deg[slot], MAXD);
    const float rinv = 1.f / (sumv[slot] + 1e-7f);
    float m = -INFINITY;
    for (int j0 = 0; j0 < d; ++j0) {
        const int j = nbr_i[slot * MAXD + j0];
        if (fu[j] >= 2 * e)
            m = fmaxf(m, nbr_e[slot * MAXD + j0] * rinv * h_tab[(size_t)j * H + c]);
    }
    Mstat[slot * H + c] = m;
    for (int j0 = c; j0 < d; j0 += 128) {
        const int j = nbr_i[slot * MAXD + j0];
        const int f = fu[j];
        if (f < 2 * e) {
            const int p = atomicAdd(&dcnt[slot], 1);
            if (p < MAXDIRTY) {
                dl_s[slot * MAXDIRTY + p] = f;
                dl_q[slot * MAXDIRTY + p] = nbr_e[slot * MAXD + j0] * rinv;
            }
            needh[f >> 1] = 1;   // h row of event f/2 is consumed later
        }
    }
}

// ---------------------------------------------------------------------------
// k_ls: lam (block 0) + survival (blocks 1..SS).
// ---------------------------------------------------------------------------
__global__ __launch_bounds__(64) void k_ls(
    const int* __restrict__ u, const int* __restrict__ v, const int* __restrict__ kk,
    const int* __restrict__ u_o, const int* __restrict__ v_o,
    const float* __restrict__ d0, const float* __restrict__ d1,
    const float* __restrict__ psi, const float* __restrict__ b_om,
    float* __restrict__ lamout, float* __restrict__ svout)
{
    const int b = threadIdx.x;
    if (blockIdx.x == 0) {
        if (b < NEV) {
            const int kv = kk[b];
            const float* dk = kv ? d1 : d0;
            const float g = 0.5f * (dk[u[b]] + dk[v[b]]) + b_om[kv];
            const float ps = psi[kv];
            const float x = fminf(75.f, fmaxf(-75.f, g / ps));
            lamout[b] = ps * log1pf(expf(x));
        }
    } else {
        const int s = blockIdx.x - 1;
        const float p0 = psi[0], p1 = psi[1], bo0 = b_om[0], bo1 = b_om[1];
        const int vo = v_o[b * SS + s], uo = u_o[b * SS + s];
        float g, x;
        g = 0.5f * (d0[u[b]] + d0[vo]) + bo0; x = fminf(75.f, fmaxf(-75.f, g / p0));
        const float ru0 = p0 * log1pf(expf(x));
        g = 0.5f * (d1[u[b]] + d1[vo]) + bo1; x = fminf(75.f, fmaxf(-75.f, g / p1));
        const float ru1 = p1 * log1pf(expf(x));
        g = 0.5f * (d1[v[b]] + d1[uo]) + bo1; x = fminf(75.f, fmaxf(-75.f, g / p1));
        const float rv1 = p1 * log1pf(expf(x));
        float val = 2.f * (ru0 + ru1) + rv1;
#pragma unroll
        for (int off = 32; off > 0; off >>= 1) val += __shfl_xor(val, off);
        if (b == 0) svout[s] = val / (float)SS;
    }
}

// ---------------------------------------------------------------------------
// k_seq: 64-event scan, 1 block x 512. Lane map c=tid&127, s=tid>>7 so every
// wave has a single s => all matvec LDS reads are wave-uniform broadcasts
// (round-3 mapping caused 398K bank-conflict cycles). State (z/h of updated
// rows) lives in LDS; phase C + 2 barriers skipped when needh[e]==0.
// ---------------------------------------------------------------------------
constexpr int KSEQ_LDS_BYTES =
    (128 * 128 * 2 /*z_upd,h_upd*/ + 128 * 4 /*hz*/ + 2 * 128 /*znw*/ +
     8 * 128 /*pr*/ + 128 /*dtv_l*/) * 4 +
    (64 + 64 + 128 + 128 + 128 + 128 + 64) * 4 /*ints*/;

__global__ __launch_bounds__(512, 2) void k_seq(
    const int* __restrict__ u, const int* __restrict__ v,
    const float* __restrict__ W_S, const float* __restrict__ W_R,
    const float* __restrict__ W_t, const float* __restrict__ W_h,
    const float* __restrict__ b_h,
    const int* __restrict__ deg, const int* __restrict__ dcnt,
    const int* __restrict__ dl_s, const float* __restrict__ dl_q,
    const float* __restrict__ Mstat,
    const int* __restrict__ zsrc, const int* __restrict__ wslot,
    const float* __restrict__ dtv, const int* __restrict__ needh,
    float* __restrict__ z_out)
{
    extern __shared__ float lds[];
    float* z_upd = lds;                 // [128][128]
    float* h_upd = z_upd + 128 * 128;   // [128][128]
    float* hz    = h_upd + 128 * 128;   // [c'][4] = {hs_v, hs_u, z_v, z_u}
    float* znw   = hz + 128 * 4;        // [r][128]
    float* pr    = znw + 2 * 128;       // [(s*2+r)][128]
    float* dtv_l = pr + 8 * 128;        // [128]
    int*   ib    = (int*)(dtv_l + 128);
    int* ev_u_l  = ib;                  // 64
    int* ev_v_l  = ib + 64;             // 64
    int* zsrc_l  = ib + 128;            // 128
    int* wslot_l = ib + 256;            // 128
    int* deg_l   = ib + 384;            // 128
    int* dcnt_l  = ib + 512;            // 128
    int* needh_l = ib + 640;            // 64

    const int tid = threadIdx.x;
    const int c = tid & 127;
    const int s = tid >> 7;             // 0..3; wave-uniform

    float wsr[32], wrr[32], whr[32];
#pragma unroll
    for (int i = 0; i < 32; ++i) {
        wsr[i] = W_S[c * H + s * 32 + i];
        wrr[i] = W_R[c * H + s * 32 + i];
        whr[i] = W_h[c * H + s * 32 + i];
    }
    const float wt_c = W_t[c];
    const float bh_c = b_h[c];

    if (tid < NEV) { ev_u_l[tid] = u[tid]; ev_v_l[tid] = v[tid]; }
    if (tid >= 64 && tid < 192)  { const int i = tid - 64;  zsrc_l[i] = zsrc[i]; wslot_l[i] = wslot[i]; }
    if (tid >= 192 && tid < 320) { const int i = tid - 192; deg_l[i] = deg[i]; dcnt_l[i] = dcnt[i]; }
    if (tid >= 320 && tid < 448) { const int i = tid - 320; dtv_l[i] = dtv[i]; }
    if (tid >= 448)              { needh_l[tid - 448] = needh[tid - 448]; }
    __syncthreads();

    // prefetch for event 0
    float mpf = 0.f, dlq0 = 0.f, zpf = 0.f;
    int dls0 = 0;
    if (tid < 256) {
        mpf  = Mstat[s * H + c];
        dls0 = dl_s[s * MAXDIRTY];
        dlq0 = dl_q[s * MAXDIRTY];
    } else {
        const int sl = zsrc_l[s - 2];
        if (sl < 0) {
            const int node = (s == 3) ? ev_u_l[0] : ev_v_l[0];
            zpf = z_out[(size_t)node * H + c];
        }
    }

    for (int e = 0; e < NEV; ++e) {
        const int uu = ev_u_l[e], vv = ev_v_l[e];
        const bool dup = (uu == vv);

        // ---- Phase A: hz = {hs_v, hs_u, z_v, z_u} ----
        if (tid < 256) {
            const int slot = e * 2 + s;         // s in {0,1} == side
            float m = mpf;
            const int nd = min(dcnt_l[slot], MAXDIRTY);
            if (nd > 0) {
                m = fmaxf(m, dlq0 * h_upd[dls0 * 128 + c]);
                for (int p = 1; p < nd; ++p) {
                    const int f2 = dl_s[slot * MAXDIRTY + p];
                    const float q2 = dl_q[slot * MAXDIRTY + p];
                    m = fmaxf(m, q2 * h_upd[f2 * 128 + c]);
                }
            }
            hz[c * 4 + s] = (deg_l[slot] > 0) ? 1.f / (1.f + __expf(-m)) : 0.f;
        } else {
            const int rz = s - 2;
            const int sl = zsrc_l[e * 2 + rz];
            hz[c * 4 + 2 + rz] = (sl >= 0) ? z_upd[sl * 128 + c] : zpf;
        }
        __syncthreads();               // B1: hz ready

        // prefetch e+1 (drains at B2 under the matvec)
        if (e + 1 < NEV) {
            if (tid < 256) {
                mpf  = Mstat[((e + 1) * 2 + s) * H + c];
                dls0 = dl_s[((e + 1) * 2 + s) * MAXDIRTY];
                dlq0 = dl_q[((e + 1) * 2 + s) * MAXDIRTY];
            } else {
                const int nsl = zsrc_l[(e + 1) * 2 + (s - 2)];
                if (nsl < 0) {
                    const int node = (s == 3) ? ev_u_l[e + 1] : ev_v_l[e + 1];
                    zpf = z_out[(size_t)node * H + c];
                }
            }
        }

        // ---- Phase B: partial g over this thread's 32-chunk ----
        {
            float a0 = 0.f, a1 = 0.f;
#pragma unroll
            for (int i = 0; i < 32; ++i) {
                const float4 vz = *(const float4*)&hz[(s * 32 + i) * 4];  // broadcast
                a0 += vz.x * wsr[i] + vz.z * wrr[i];
                a1 += vz.y * wsr[i] + vz.w * wrr[i];
            }
            pr[(s * 2 + 0) * 128 + c] = a0;
            pr[(s * 2 + 1) * 128 + c] = a1;
        }
        __syncthreads();               // B2: partials ready

        if (tid < 256) {
            const int r = s;
            float g = pr[(0 * 2 + r) * 128 + c] + pr[(1 * 2 + r) * 128 + c] +
                      pr[(2 * 2 + r) * 128 + c] + pr[(3 * 2 + r) * 128 + c];
            g += dtv_l[e * 2 + r] * wt_c;
            const float zv = 1.f / (1.f + __expf(-g));
            znw[r * 128 + c] = zv;
            if (!(dup && r == 0)) z_upd[wslot_l[e * 2 + r] * 128 + c] = zv;
        }
        __syncthreads();               // B3: znw/z_upd ready

        // ---- Phase C (only when some later event reads these h rows) ----
        if (needh_l[e]) {              // uniform branch
            float b0 = 0.f, b1 = 0.f;
#pragma unroll
            for (int i4 = 0; i4 < 8; ++i4) {
                const float4 z0 = *(const float4*)&znw[0 * 128 + s * 32 + i4 * 4];
                const float4 z1 = *(const float4*)&znw[1 * 128 + s * 32 + i4 * 4];
                b0 += z0.x * whr[i4 * 4] + z0.y * whr[i4 * 4 + 1] +
                      z0.z * whr[i4 * 4 + 2] + z0.w * whr[i4 * 4 + 3];
                b1 += z1.x * whr[i4 * 4] + z1.y * whr[i4 * 4 + 1] +
                      z1.z * whr[i4 * 4 + 2] + z1.w * whr[i4 * 4 + 3];
            }
            pr[(s * 2 + 0) * 128 + c] = b0;
            pr[(s * 2 + 1) * 128 + c] = b1;
            __syncthreads();           // B4
            if (tid < 256 && !(dup && s == 0)) {
                const float hval = pr[(0 * 2 + s) * 128 + c] + pr[(1 * 2 + s) * 128 + c] +
                                   pr[(2 * 2 + s) * 128 + c] + pr[(3 * 2 + s) * 128 + c] + bh_c;
                h_upd[wslot_l[e * 2 + s] * 128 + c] = hval;
            }
            __syncthreads();           // B5
        }
    }

    // ---- flush canonical slots, coalesced: lane = column ----
    for (int sl = s; sl < 128; sl += 4) {
        if (wslot_l[sl] == sl) {
            const int node = (sl & 1) ? ev_u_l[sl >> 1] : ev_v_l[sl >> 1];
            z_out[(size_t)node * H + c] = z_upd[sl * 128 + c];
        }
    }
}

// ---------------------------------------------------------------------------
extern "C" void kernel_launch(void* const* d_in, const int* in_sizes, int n_in,
                              void* d_out, int out_size, void* d_ws, size_t ws_size,
                              hipStream_t stream)
{
    const int*   u        = (const int*)d_in[0];
    const int*   v        = (const int*)d_in[1];
    const float* t        = (const float*)d_in[2];
    const int*   k        = (const int*)d_in[3];
    const int*   u_others = (const int*)d_in[4];
    const int*   v_others = (const int*)d_in[5];
    const float* A        = (const float*)d_in[6];
    const float* S        = (const float*)d_in[7];
    const float* emb      = (const float*)d_in[8];
    const float* lastt    = (const float*)d_in[9];
    const float* W_S      = (const float*)d_in[10];
    const float* W_R      = (const float*)d_in[11];
    const float* W_t      = (const float*)d_in[12];
    const float* W_h      = (const float*)d_in[13];
    const float* b_h      = (const float*)d_in[14];
    const float* psi      = (const float*)d_in[15];
    const float* W_om     = (const float*)d_in[16];
    const float* b_om     = (const float*)d_in[17];
    (void)in_sizes; (void)n_in; (void)out_size; (void)ws_size;

    float* wsf   = (float*)d_ws;
    float* h_tab = wsf;                           // N*H
    float* d0    = h_tab + (size_t)N * H;         // N
    float* d1    = d0 + N;                        // N
    float* sumv  = d1 + N;                        // 128
    float* nbre  = sumv + 128;                    // 128*MAXD
    float* Mstat = nbre + 128 * MAXD;             // 128*H
    float* dl_q  = Mstat + 128 * H;               // 128*MAXDIRTY
    float* dtv   = dl_q + 128 * MAXDIRTY;         // 128
    int*   deg   = (int*)(dtv + 128);             // 128
    int*   dcnt  = deg + 128;                     // 128
    int*   nbri  = dcnt + 128;                    // 128*MAXD
    int*   dl_s  = nbri + 128 * MAXD;             // 128*MAXDIRTY
    int*   fu    = dl_s + 128 * MAXDIRTY;         // N
    int*   zsrc  = fu + N;                        // 128
    int*   wslot = zsrc + 128;                    // 128
    int*   needh = wslot + 128;                   // 64

    float* out    = (float*)d_out;
    float* lamout = out;            // [64]
    float* svout  = out + NEV;      // [20]
    float* z_out  = out + NEV + SS; // [N*H]

    hipFuncSetAttribute((const void*)k_seq,
                        hipFuncAttributeMaxDynamicSharedMemorySize,
                        KSEQ_LDS_BYTES);

    k_init<<<1, 256, 0, stream>>>(u, v, t, lastt, fu, zsrc, wslot, dtv, deg, dcnt, needh);
    k_emb<<<N / RPB, 512, 0, stream>>>(emb, W_h, b_h, W_om, h_tab, z_out, d0, d1);
    k_nbr<<<128, 256, 0, stream>>>(u, v, A, S, deg, sumv, nbri, nbre);
    k_dm<<<128, 128, 0, stream>>>(deg, sumv, nbri, nbre, fu, h_tab, Mstat, dcnt, dl_s, dl_q, needh);
    k_ls<<<SS + 1, 64, 0, stream>>>(u, v, k, u_others, v_others, d0, d1, psi, b_om, lamout, svout);
    k_seq<<<1, 512, KSEQ_LDS_BYTES, stream>>>(u, v, W_S, W_R, W_t, W_h, b_h,
                                              deg, dcnt, dl_s, dl_q, Mstat,
                                              zsrc, wslot, dtv, needh, z_out);
}

// Round 6
// 178.772 us; speedup vs baseline: 2.0045x; 1.0017x over previous
//
#include <hip/hip_runtime.h>
#include <math.h>

#define N 8192
#define H 128
#define NEV 64
#define SS 20
#define MAXD 512
#define MAXDIRTY 128
#define RPB 32

// ---------------------------------------------------------------------------
// k_init: fu[n] = first updater-slot id (slot = e*2+i; i=0 -> row v[e],
// i=1 -> row u[e]); zsrc[slot] = canonical slot if node updated before event e
// else -1; wslot[slot] = canonical slot; dtv[slot] = precomputed dt.
// Zeroes deg/dcnt/needh.
// ---------------------------------------------------------------------------
__global__ __launch_bounds__(256) void k_init(
    const int* __restrict__ u, const int* __restrict__ v,
    const float* __restrict__ t, const float* __restrict__ lastt,
    int* __restrict__ fu, int* __restrict__ zsrc, int* __restrict__ wslot,
    float* __restrict__ dtv, int* __restrict__ deg, int* __restrict__ dcnt,
    int* __restrict__ needh)
{
    __shared__ int fuL[N];   // 32 KB
    const int tid = threadIdx.x;
    for (int i = tid; i < N; i += 256) fuL[i] = 0x7FFFFFFF;
    if (tid < 128) { deg[tid] = 0; dcnt[tid] = 0; }
    if (tid < NEV) needh[tid] = 0;
    __syncthreads();
    if (tid < 2 * NEV) {
        const int e = tid >> 1, i = tid & 1;
        const int node = i ? u[e] : v[e];       // i=0 -> row v, i=1 -> row u
        atomicMin(&fuL[node], tid);
    }
    __syncthreads();
    for (int i = tid; i < N; i += 256) fu[i] = fuL[i];
    if (tid < 2 * NEV) {
        const int e = tid >> 1, i = tid & 1;
        const int node = i ? u[e] : v[e];
        const int f = fuL[node];
        wslot[tid] = f;
        zsrc[tid] = (f < 2 * e) ? f : -1;       // updated strictly before event e?
        const int dtn = i ? v[e] : u[e];        // crossed: row v uses let[u], row u let[v]
        int pt = -1;
        for (int e2 = e - 1; e2 >= 0; --e2)
            if (u[e2] == dtn || v[e2] == dtn) { pt = e2; break; }
        const float lv = (pt >= 0) ? t[pt] : lastt[dtn];
        dtv[tid] = t[e] - lv;
    }
}

// ---------------------------------------------------------------------------
// k_emb: h_tab = emb @ W_h.T + b_h ; z_out = emb copy ; d0/d1 rate dots.
// ---------------------------------------------------------------------------
__global__ __launch_bounds__(512) void k_emb(
    const float* __restrict__ emb, const float* __restrict__ W_h,
    const float* __restrict__ b_h, const float* __restrict__ W_om,
    float* __restrict__ h_tab, float* __restrict__ z_out,
    float* __restrict__ d0, float* __restrict__ d1)
{
    const int tid = threadIdx.x;
    const int c = tid & 127;
    const int s = tid >> 7;             // 0..3
    const int r0 = blockIdx.x * RPB;

    __shared__ __align__(16) float z4[4 * 128];
    __shared__ float pr[8 * 128];

    float whr[32];
#pragma unroll
    for (int i = 0; i < 32; ++i) whr[i] = W_h[c * H + s * 32 + i];
    const float bh_c = b_h[c];

    const int lane = tid & 63;
    const int wid = tid >> 6;
    const int kof = (wid >= 4) ? 256 : 0;
    const float wk_l = W_om[kof + lane]      + W_om[kof + 128 + lane];
    const float wk_h = W_om[kof + 64 + lane] + W_om[kof + 192 + lane];

    for (int b = 0; b < RPB / 4; ++b) {
        const int rbase = r0 + b * 4;
        __syncthreads();
        const float zv = emb[(size_t)rbase * H + tid];
        z4[tid] = zv;
        z_out[(size_t)rbase * H + tid] = zv;
        __syncthreads();

#pragma unroll
        for (int rr = 0; rr < 4; ++rr) {
            float a = 0.f;
#pragma unroll
            for (int i4 = 0; i4 < 8; ++i4) {
                const float4 zz = *(const float4*)&z4[rr * 128 + s * 32 + i4 * 4];
                a += zz.x * whr[i4 * 4] + zz.y * whr[i4 * 4 + 1] +
                     zz.z * whr[i4 * 4 + 2] + zz.w * whr[i4 * 4 + 3];
            }
            pr[(s * 4 + rr) * 128 + c] = a;
        }
        {
            const int rr = wid & 3;
            float val = z4[rr * 128 + lane] * wk_l + z4[rr * 128 + 64 + lane] * wk_h;
#pragma unroll
            for (int off = 32; off > 0; off >>= 1) val += __shfl_xor(val, off);
            if (lane == 0) {
                if (wid < 4) d0[rbase + rr] = val;
                else         d1[rbase + rr] = val;
            }
        }
        __syncthreads();
        {
            const int rr = s;
            const float h = pr[(0 * 4 + rr) * 128 + c] + pr[(1 * 4 + rr) * 128 + c] +
                            pr[(2 * 4 + rr) * 128 + c] + pr[(3 * 4 + rr) * 128 + c] + bh_c;
            h_tab[(size_t)(rbase + rr) * H + c] = h;
        }
    }
}

// ---------------------------------------------------------------------------
// k_nbr: compact neighbor lists for the 128 (event,side) rows.
// ---------------------------------------------------------------------------
__global__ __launch_bounds__(256) void k_nbr(
    const int* __restrict__ u, const int* __restrict__ v,
    const float* __restrict__ A, const float* __restrict__ S,
    int* __restrict__ deg, float* __restrict__ sumv,
    int* __restrict__ nbr_i, float* __restrict__ nbr_e)
{
    const int slot = blockIdx.x;
    const int e = slot >> 1, side = slot & 1;
    const int row = (side == 0) ? v[e] : u[e];
    const size_t base = (size_t)row * N;
    const int tid = threadIdx.x;
    float lsum = 0.f;
    for (int j = tid; j < N; j += 256) {
        if (A[base + j] > 0.f) {
            const float ev = expf(S[base + j]);
            lsum += ev;
            const int p = atomicAdd(&deg[slot], 1);
            if (p < MAXD) {
                nbr_i[slot * MAXD + p] = j;
                nbr_e[slot * MAXD + p] = ev;
            }
        }
    }
    __shared__ float rs[256];
    rs[tid] = lsum;
    __syncthreads();
    for (int off = 128; off > 0; off >>= 1) {
        if (tid < off) rs[tid] += rs[tid + off];
        __syncthreads();
    }
    if (tid == 0) sumv[slot] = rs[0];
}

// ---------------------------------------------------------------------------
// k_dm: Mstat over static neighbors + dirty list (with canonical slots) +
// needh[e'] flag for events whose h rows are later consumed.
// ---------------------------------------------------------------------------
__global__ __launch_bounds__(128) void k_dm(
    const int* __restrict__ deg, const float* __restrict__ sumv,
    const int* __restrict__ nbr_i, const float* __restrict__ nbr_e,
    const int* __restrict__ fu, const float* __restrict__ h_tab,
    float* __restrict__ Mstat, int* __restrict__ dcnt,
    int* __restrict__ dl_s, float* __restrict__ dl_q,
    int* __restrict__ needh)
{
    const int slot = blockIdx.x;
    const int e = slot >> 1;
    const int c = threadIdx.x;
    const int d = min(deg[slot], MAXD);
    const float rinv = 1.f / (sumv[slot] + 1e-7f);
    float m = -INFINITY;
    for (int j0 = 0; j0 < d; ++j0) {
        const int j = nbr_i[slot * MAXD + j0];
        if (fu[j] >= 2 * e)
            m = fmaxf(m, nbr_e[slot * MAXD + j0] * rinv * h_tab[(size_t)j * H + c]);
    }
    Mstat[slot * H + c] = m;
    for (int j0 = c; j0 < d; j0 += 128) {
        const int j = nbr_i[slot * MAXD + j0];
        const int f = fu[j];
        if (f < 2 * e) {
            const int p = atomicAdd(&dcnt[slot], 1);
            if (p < MAXDIRTY) {
                dl_s[slot * MAXDIRTY + p] = f;
                dl_q[slot * MAXDIRTY + p] = nbr_e[slot * MAXD + j0] * rinv;
            }
            needh[f >> 1] = 1;   // h row of event f/2 is consumed later
        }
    }
}

// ---------------------------------------------------------------------------
// k_ls: lam (block 0) + survival (blocks 1..SS).
// ---------------------------------------------------------------------------
__global__ __launch_bounds__(64) void k_ls(
    const int* __restrict__ u, const int* __restrict__ v, const int* __restrict__ kk,
    const int* __restrict__ u_o, const int* __restrict__ v_o,
    const float* __restrict__ d0, const float* __restrict__ d1,
    const float* __restrict__ psi, const float* __restrict__ b_om,
    float* __restrict__ lamout, float* __restrict__ svout)
{
    const int b = threadIdx.x;
    if (blockIdx.x == 0) {
        if (b < NEV) {
            const int kv = kk[b];
            const float* dk = kv ? d1 : d0;
            const float g = 0.5f * (dk[u[b]] + dk[v[b]]) + b_om[kv];
            const float ps = psi[kv];
            const float x = fminf(75.f, fmaxf(-75.f, g / ps));
            lamout[b] = ps * log1pf(expf(x));
        }
    } else {
        const int s = blockIdx.x - 1;
        const float p0 = psi[0], p1 = psi[1], bo0 = b_om[0], bo1 = b_om[1];
        const int vo = v_o[b * SS + s], uo = u_o[b * SS + s];
        float g, x;
        g = 0.5f * (d0[u[b]] + d0[vo]) + bo0; x = fminf(75.f, fmaxf(-75.f, g / p0));
        const float ru0 = p0 * log1pf(expf(x));
        g = 0.5f * (d1[u[b]] + d1[vo]) + bo1; x = fminf(75.f, fmaxf(-75.f, g / p1));
        const float ru1 = p1 * log1pf(expf(x));
        g = 0.5f * (d1[v[b]] + d1[uo]) + bo1; x = fminf(75.f, fmaxf(-75.f, g / p1));
        const float rv1 = p1 * log1pf(expf(x));
        float val = 2.f * (ru0 + ru1) + rv1;
#pragma unroll
        for (int off = 32; off > 0; off >>= 1) val += __shfl_xor(val, off);
        if (b == 0) svout[s] = val / (float)SS;
    }
}

// ---------------------------------------------------------------------------
// k_seq: 64-event scan, 1 block x 512. Identical to the round-4 (passing)
// version except __launch_bounds__(512, 1): the (512,2) bound capped the
// allocator at 128 VGPRs, forcing the 96 W_S/W_R/W_h values out of registers
// and onto ~96 L2 re-loads per event on the critical path (VGPR_Count=76).
// With min-waves=1 the cap is 512 and the pinned weight arrays stay resident.
// ---------------------------------------------------------------------------
constexpr int KSEQ_LDS_BYTES =
    (128 * 128 * 2 /*z_upd,h_upd*/ + 128 * 4 /*hz*/ + 2 * 128 /*znw*/ +
     8 * 128 /*pr*/ + 128 /*dtv_l*/) * 4 +
    (64 + 64 + 128 + 128 + 128 + 128 + 64) * 4 /*ints*/;

__global__ __launch_bounds__(512, 1) void k_seq(
    const int* __restrict__ u, const int* __restrict__ v,
    const float* __restrict__ W_S, const float* __restrict__ W_R,
    const float* __restrict__ W_t, const float* __restrict__ W_h,
    const float* __restrict__ b_h,
    const int* __restrict__ deg, const int* __restrict__ dcnt,
    const int* __restrict__ dl_s, const float* __restrict__ dl_q,
    const float* __restrict__ Mstat,
    const int* __restrict__ zsrc, const int* __restrict__ wslot,
    const float* __restrict__ dtv, const int* __restrict__ needh,
    float* __restrict__ z_out)
{
    extern __shared__ float lds[];
    float* z_upd = lds;                 // [128][128]
    float* h_upd = z_upd + 128 * 128;   // [128][128]
    float* hz    = h_upd + 128 * 128;   // [c'][4] = {hs_v, hs_u, z_v, z_u}
    float* znw   = hz + 128 * 4;        // [r][128]
    float* pr    = znw + 2 * 128;       // [(s*2+r)][128]
    float* dtv_l = pr + 8 * 128;        // [128]
    int*   ib    = (int*)(dtv_l + 128);
    int* ev_u_l  = ib;                  // 64
    int* ev_v_l  = ib + 64;             // 64
    int* zsrc_l  = ib + 128;            // 128
    int* wslot_l = ib + 256;            // 128
    int* deg_l   = ib + 384;            // 128
    int* dcnt_l  = ib + 512;            // 128
    int* needh_l = ib + 640;            // 64

    const int tid = threadIdx.x;
    const int c = tid & 127;
    const int s = tid >> 7;             // 0..3; wave-uniform

    float wsr[32], wrr[32], whr[32];
#pragma unroll
    for (int i = 0; i < 32; ++i) {
        wsr[i] = W_S[c * H + s * 32 + i];
        wrr[i] = W_R[c * H + s * 32 + i];
        whr[i] = W_h[c * H + s * 32 + i];
    }
    const float wt_c = W_t[c];
    const float bh_c = b_h[c];

    if (tid < NEV) { ev_u_l[tid] = u[tid]; ev_v_l[tid] = v[tid]; }
    if (tid >= 64 && tid < 192)  { const int i = tid - 64;  zsrc_l[i] = zsrc[i]; wslot_l[i] = wslot[i]; }
    if (tid >= 192 && tid < 320) { const int i = tid - 192; deg_l[i] = deg[i]; dcnt_l[i] = dcnt[i]; }
    if (tid >= 320 && tid < 448) { const int i = tid - 320; dtv_l[i] = dtv[i]; }
    if (tid >= 448)              { needh_l[tid - 448] = needh[tid - 448]; }
    __syncthreads();

    // prefetch for event 0
    float mpf = 0.f, dlq0 = 0.f, zpf = 0.f;
    int dls0 = 0;
    if (tid < 256) {
        mpf  = Mstat[s * H + c];
        dls0 = dl_s[s * MAXDIRTY];
        dlq0 = dl_q[s * MAXDIRTY];
    } else {
        const int sl = zsrc_l[s - 2];
        if (sl < 0) {
            const int node = (s == 3) ? ev_u_l[0] : ev_v_l[0];
            zpf = z_out[(size_t)node * H + c];
        }
    }

    for (int e = 0; e < NEV; ++e) {
        // pin weights live across the loop (prevent rematerialization)
#pragma unroll
        for (int i = 0; i < 32; ++i)
            asm volatile("" : "+v"(wsr[i]), "+v"(wrr[i]), "+v"(whr[i]));

        const int uu = ev_u_l[e], vv = ev_v_l[e];
        const bool dup = (uu == vv);

        // ---- Phase A: hz = {hs_v, hs_u, z_v, z_u} ----
        if (tid < 256) {
            const int slot = e * 2 + s;
            float m = mpf;
            const int nd = min(dcnt_l[slot], MAXDIRTY);
            if (nd > 0) {
                m = fmaxf(m, dlq0 * h_upd[dls0 * 128 + c]);
                for (int p = 1; p < nd; ++p) {
                    const int f2 = dl_s[slot * MAXDIRTY + p];
                    const float q2 = dl_q[slot * MAXDIRTY + p];
                    m = fmaxf(m, q2 * h_upd[f2 * 128 + c]);
                }
            }
            hz[c * 4 + s] = (deg_l[slot] > 0) ? 1.f / (1.f + __expf(-m)) : 0.f;
        } else {
            const int rz = s - 2;
            const int sl = zsrc_l[e * 2 + rz];
            hz[c * 4 + 2 + rz] = (sl >= 0) ? z_upd[sl * 128 + c] : zpf;
        }
        __syncthreads();               // B1: hz ready

        // prefetch e+1 (all sources immutable during the loop)
        if (e + 1 < NEV) {
            if (tid < 256) {
                mpf  = Mstat[((e + 1) * 2 + s) * H + c];
                dls0 = dl_s[((e + 1) * 2 + s) * MAXDIRTY];
                dlq0 = dl_q[((e + 1) * 2 + s) * MAXDIRTY];
            } else {
                const int nsl = zsrc_l[(e + 1) * 2 + (s - 2)];
                if (nsl < 0) {
                    const int node = (s == 3) ? ev_u_l[e + 1] : ev_v_l[e + 1];
                    zpf = z_out[(size_t)node * H + c];
                }
            }
        }

        // ---- Phase B partial: 32-chunk of both rows ----
        {
            float a0 = 0.f, a1 = 0.f;
#pragma unroll
            for (int i = 0; i < 32; ++i) {
                const float4 vz = *(const float4*)&hz[(s * 32 + i) * 4];  // broadcast
                a0 += vz.x * wsr[i] + vz.z * wrr[i];
                a1 += vz.y * wsr[i] + vz.w * wrr[i];
            }
            pr[(s * 2 + 0) * 128 + c] = a0;
            pr[(s * 2 + 1) * 128 + c] = a1;
        }
        __syncthreads();               // B2: partials ready

        // ---- Phase B final ----
        if (tid < 256) {
            const int r = s;
            float g = pr[(0 * 2 + r) * 128 + c] + pr[(1 * 2 + r) * 128 + c] +
                      pr[(2 * 2 + r) * 128 + c] + pr[(3 * 2 + r) * 128 + c];
            g += dtv_l[e * 2 + r] * wt_c;
            const float zv = 1.f / (1.f + __expf(-g));
            znw[r * 128 + c] = zv;
            if (!(dup && r == 0)) z_upd[wslot_l[e * 2 + r] * 128 + c] = zv;
        }
        __syncthreads();               // B3: znw/z_upd ready

        // ---- Phase C (only when some later event reads these h rows) ----
        if (needh_l[e]) {              // uniform branch
            float b0 = 0.f, b1 = 0.f;
#pragma unroll
            for (int i4 = 0; i4 < 8; ++i4) {
                const float4 z0 = *(const float4*)&znw[0 * 128 + s * 32 + i4 * 4];
                const float4 z1 = *(const float4*)&znw[1 * 128 + s * 32 + i4 * 4];
                b0 += z0.x * whr[i4 * 4] + z0.y * whr[i4 * 4 + 1] +
                      z0.z * whr[i4 * 4 + 2] + z0.w * whr[i4 * 4 + 3];
                b1 += z1.x * whr[i4 * 4] + z1.y * whr[i4 * 4 + 1] +
                      z1.z * whr[i4 * 4 + 2] + z1.w * whr[i4 * 4 + 3];
            }
            pr[(s * 2 + 0) * 128 + c] = b0;
            pr[(s * 2 + 1) * 128 + c] = b1;
            __syncthreads();           // B4
            if (tid < 256 && !(dup && s == 0)) {
                const float hval = pr[(0 * 2 + s) * 128 + c] + pr[(1 * 2 + s) * 128 + c] +
                                   pr[(2 * 2 + s) * 128 + c] + pr[(3 * 2 + s) * 128 + c] + bh_c;
                h_upd[wslot_l[e * 2 + s] * 128 + c] = hval;
            }
            __syncthreads();           // B5
        }
    }

    // ---- flush canonical slots, coalesced: lane = column ----
    for (int sl = s; sl < 128; sl += 4) {
        if (wslot_l[sl] == sl) {
            const int node = (sl & 1) ? ev_u_l[sl >> 1] : ev_v_l[sl >> 1];
            z_out[(size_t)node * H + c] = z_upd[sl * 128 + c];
        }
    }
}

// ---------------------------------------------------------------------------
extern "C" void kernel_launch(void* const* d_in, const int* in_sizes, int n_in,
                              void* d_out, int out_size, void* d_ws, size_t ws_size,
                              hipStream_t stream)
{
    const int*   u        = (const int*)d_in[0];
    const int*   v        = (const int*)d_in[1];
    const float* t        = (const float*)d_in[2];
    const int*   k        = (const int*)d_in[3];
    const int*   u_others = (const int*)d_in[4];
    const int*   v_others = (const int*)d_in[5];
    const float* A        = (const float*)d_in[6];
    const float* S        = (const float*)d_in[7];
    const float* emb      = (const float*)d_in[8];
    const float* lastt    = (const float*)d_in[9];
    const float* W_S      = (const float*)d_in[10];
    const float* W_R      = (const float*)d_in[11];
    const float* W_t      = (const float*)d_in[12];
    const float* W_h      = (const float*)d_in[13];
    const float* b_h      = (const float*)d_in[14];
    const float* psi      = (const float*)d_in[15];
    const float* W_om     = (const float*)d_in[16];
    const float* b_om     = (const float*)d_in[17];
    (void)in_sizes; (void)n_in; (void)out_size; (void)ws_size;

    float* wsf   = (float*)d_ws;
    float* h_tab = wsf;                           // N*H
    float* d0    = h_tab + (size_t)N * H;         // N
    float* d1    = d0 + N;                        // N
    float* sumv  = d1 + N;                        // 128
    float* nbre  = sumv + 128;                    // 128*MAXD
    float* Mstat = nbre + 128 * MAXD;             // 128*H
    float* dl_q  = Mstat + 128 * H;               // 128*MAXDIRTY
    float* dtv   = dl_q + 128 * MAXDIRTY;         // 128
    int*   deg   = (int*)(dtv + 128);             // 128
    int*   dcnt  = deg + 128;                     // 128
    int*   nbri  = dcnt + 128;                    // 128*MAXD
    int*   dl_s  = nbri + 128 * MAXD;             // 128*MAXDIRTY
    int*   fu    = dl_s + 128 * MAXDIRTY;         // N
    int*   zsrc  = fu + N;                        // 128
    int*   wslot = zsrc + 128;                    // 128
    int*   needh = wslot + 128;                   // 64

    float* out    = (float*)d_out;
    float* lamout = out;            // [64]
    float* svout  = out + NEV;      // [20]
    float* z_out  = out + NEV + SS; // [N*H]

    hipFuncSetAttribute((const void*)k_seq,
                        hipFuncAttributeMaxDynamicSharedMemorySize,
                        KSEQ_LDS_BYTES);

    k_init<<<1, 256, 0, stream>>>(u, v, t, lastt, fu, zsrc, wslot, dtv, deg, dcnt, needh);
    k_emb<<<N / RPB, 512, 0, stream>>>(emb, W_h, b_h, W_om, h_tab, z_out, d0, d1);
    k_nbr<<<128, 256, 0, stream>>>(u, v, A, S, deg, sumv, nbri, nbre);
    k_dm<<<128, 128, 0, stream>>>(deg, sumv, nbri, nbre, fu, h_tab, Mstat, dcnt, dl_s, dl_q, needh);
    k_ls<<<SS + 1, 64, 0, stream>>>(u, v, k, u_others, v_others, d0, d1, psi, b_om, lamout, svout);
    k_seq<<<1, 512, KSEQ_LDS_BYTES, stream>>>(u, v, W_S, W_R, W_t, W_h, b_h,
                                              deg, dcnt, dl_s, dl_q, Mstat,
                                              zsrc, wslot, dtv, needh, z_out);
}